// Round 22
// baseline (38.971 us; speedup 1.0000x reference)
//
#include <hip/hip_runtime.h>

// PSROI pooling: fsam (N=8, C=245, H=80, W=80) f32, box (R=8192, 5) f32
// out (R, 245) f32. out[r, c] = mean over fsam[b, c, hs:he, ws:we].
//
// ARITHMETIC (frozen since R10, DO NOT TOUCH): bin = roi * fl32(1/7)
// (reciprocal multiply, 0x3E124925) and edges = SEPARATELY-rounded
// g*bin + off (asm barriers). Matches ref (absmax <= 0.016 << 0.0725).
//
// R21: single-buffer + full occupancy. R20's double buffer cost LDS
// (53.8KB -> only 2 blocks/CU = 16 waves) and its 736-block grid ran 1.44
// uneven scheduling waves. Now: ONE 26.9KB buffer (4 blocks x 512 thr =
// 2048 thr/CU = 32 waves, the CU max), grid 8 images x 123 = 984 blocks
// ~ one uniform wave on 1024 slots; block s owns planes c = s, s+123.
// Pipeline kept: plane k+1's float4s load into REGISTERS right after
// plane k's first barrier; ds_write waits one extra barrier (pool-k done).
// Cross-block phase stagger (4/CU) now provides the overlap the second
// buffer used to. Scans/pool/bucket/edge math verbatim -> bit-identical.

#define N_ 8
#define C_ 245
#define H_ 80
#define W_ 80
#define R_ 8192
#define P_ 7
#define SROW 84                    // row stride in floats (21 float4)

// XLA-style separately-rounded a*b + c in f32; barriers forbid contraction.
__device__ __forceinline__ float sep_ma(float a, float b, float c) {
    float p = a * b;                 // v_mul_f32, IEEE RN
    asm volatile("" : "+v"(p));      // contraction barrier
    float s = p + c;                 // v_add_f32, IEEE RN
    asm volatile("" : "+v"(s));
    return s;
}

// ---- kernel 1: deterministic bucket build (8 blocks, no atomics) ----
__global__ __launch_bounds__(256) void bucket_kernel(
    const float* __restrict__ box, int* __restrict__ cnt,
    int* __restrict__ buckets)
{
    __shared__ int psum[256];
    int b = blockIdx.x;                    // image
    int t = threadIdx.x;
    int r0 = t * 32;                       // contiguous range per thread

    unsigned match = 0u;
    int m = 0;
    #pragma unroll
    for (int k = 0; k < 32; ++k) {
        int bb = (int)box[(size_t)(r0 + k) * 5];
        if (bb == b) { match |= 1u << k; ++m; }
    }
    psum[t] = m;
    __syncthreads();

    for (int off = 1; off < 256; off <<= 1) {
        int v = (t >= off) ? psum[t - off] : 0;
        __syncthreads();
        psum[t] += v;
        __syncthreads();
    }
    int pos = psum[t] - m;                 // exclusive prefix
    for (int k = 0; k < 32; ++k)
        if (match & (1u << k)) buckets[b * R_ + pos++] = r0 + k;
    if (t == 255) cnt[b] = psum[255];
}

__device__ __forceinline__ float4 f4_add(float4 a, float4 b) {
    return make_float4(a.x + b.x, a.y + b.y, a.z + b.z, a.w + b.w);
}

// ---- kernel 2: persistent 2-plane blocks, single LDS buffer ----
__global__ __launch_bounds__(512) void fused_kernel(
    const float* __restrict__ fsam,
    const float* __restrict__ box,
    const int* __restrict__ cnt,
    const int* __restrict__ buckets,
    float* __restrict__ out)
{
    __shared__ float B[H_ * SROW];         // 26880 B
    int id  = blockIdx.x;                  // 0..983
    int b   = id & 7;                      // image (XCD swizzle: XCD = b)
    int s   = id >> 3;                     // 0..122
    int np  = (s + 123 < C_) ? 2 : 1;      // planes: c = s, s+123
    int tid = threadIdx.x;

    int n  = cnt[b];
    const int* lst = buckets + b * R_;

    // register staging for one plane (1600 float4 / 512 threads)
    float4 ld0, ld1, ld2, ld3;
    auto do_load = [&](int c) {
        const float4* src = (const float4*)(fsam + ((size_t)b * C_ + c) * (H_ * W_));
        ld0 = src[tid];
        ld1 = src[tid + 512];
        ld2 = src[tid + 1024];
        if (tid < 64) ld3 = src[tid + 1536];
    };
    auto wr1 = [&](int i, float4 v) {
        int row = (int)((unsigned)i / 20u);
        int c4  = i - row * 20;
        ((float4*)B)[row * 21 + c4] = v;
    };
    auto do_write = [&]() {
        wr1(tid,        ld0);
        wr1(tid +  512, ld1);
        wr1(tid + 1024, ld2);
        if (tid < 64) wr1(tid + 1536, ld3);
    };

    do_load(s);                            // prologue: plane 0

    for (int k = 0; k < np; ++k) {
        int c = s + 123 * k;

        do_write();
        __syncthreads();                   // raw plane ready in B

        if (k + 1 < np) do_load(s + 123);  // hides under scans+pool

        // ---- horizontal scan: 80 rows x 4 chunks of 20, in registers ----
        if (tid < 320) {
            int row = tid >> 2, q = tid & 3;
            float4* base = (float4*)B + row * 21 + q * 5;
            float v[20];
            #pragma unroll
            for (int kk = 0; kk < 5; ++kk) {
                float4 t = base[kk];
                v[4*kk+0] = t.x; v[4*kk+1] = t.y; v[4*kk+2] = t.z; v[4*kk+3] = t.w;
            }
            float run = 0.0f;
            #pragma unroll
            for (int j = 0; j < 20; ++j) { run += v[j]; v[j] = run; }
            float incl = run;
            #pragma unroll
            for (int d = 1; d < 4; d <<= 1) {
                float u = __shfl_up(incl, d, 4);
                if (q >= d) incl += u;
            }
            float off = incl - run;
            #pragma unroll
            for (int j = 0; j < 20; ++j) v[j] += off;
            #pragma unroll
            for (int kk = 0; kk < 5; ++kk)
                base[kk] = make_float4(v[4*kk+0], v[4*kk+1], v[4*kk+2], v[4*kk+3]);
        }
        __syncthreads();

        // ---- vertical scan: 20 col-groups x 16 chunks of 5 rows ----
        if (tid < 320) {
            int cg = tid >> 4;             // 0..19
            int ch = tid & 15;             // 0..15
            float4* col = (float4*)B + cg;
            float4 v[5];
            float4 run = make_float4(0.f, 0.f, 0.f, 0.f);
            #pragma unroll
            for (int j = 0; j < 5; ++j) {
                run = f4_add(run, col[(ch * 5 + j) * 21]);
                v[j] = run;
            }
            float4 incl = run;
            #pragma unroll
            for (int d = 1; d < 16; d <<= 1) {
                float4 u;
                u.x = __shfl_up(incl.x, d, 16);
                u.y = __shfl_up(incl.y, d, 16);
                u.z = __shfl_up(incl.z, d, 16);
                u.w = __shfl_up(incl.w, d, 16);
                if (ch >= d) incl = f4_add(incl, u);
            }
            float4 off = make_float4(incl.x - run.x, incl.y - run.y,
                                     incl.z - run.z, incl.w - run.w);
            #pragma unroll
            for (int j = 0; j < 5; ++j)
                col[(ch * 5 + j) * 21] = f4_add(v[j], off);
        }
        __syncthreads();

        // ---- pool this image's ROIs from SAT in B ----
        int ph = (c / P_) % P_;            // block-uniform
        int pw = c % P_;

        for (int i = tid; i < n; i += 512) {
            int r = lst[i];
            const float* bx = box + (size_t)r * 5;

            // ---- R10-frozen edge arithmetic ----
            float x1 = rintf(bx[1]);
            float y1 = rintf(bx[2]);
            float x2 = rintf(bx[3] + 1.0f);
            float y2 = rintf(bx[4] + 1.0f);

            float roi_w = fmaxf(x2 - x1, 0.1f);
            float roi_h = fmaxf(y2 - y1, 0.1f);

            const float RCP7 = __uint_as_float(0x3E124925u); // fl32(1/7)
            float bin_w = roi_w * RCP7;
            float bin_h = roi_h * RCP7;
            asm volatile("" : "+v"(bin_w), "+v"(bin_h));

            float hs_f = floorf(sep_ma((float)ph,       bin_h, y1));
            float he_f = ceilf (sep_ma((float)(ph + 1), bin_h, y1));
            float ws_f = floorf(sep_ma((float)pw,       bin_w, x1));
            float we_f = ceilf (sep_ma((float)(pw + 1), bin_w, x1));

            int hs = (int)fminf(fmaxf(hs_f, 0.0f), 80.0f);
            int he = (int)fminf(fmaxf(he_f, 0.0f), 80.0f);
            int ws = (int)fminf(fmaxf(ws_f, 0.0f), 80.0f);
            int we = (int)fminf(fmaxf(we_f, 0.0f), 80.0f);

            // SAT taps with implicit zero row/col (clamp + select)
            int i1 = he > 0 ? he - 1 : 0, i0 = hs > 0 ? hs - 1 : 0;
            int j1 = we > 0 ? we - 1 : 0, j0 = ws > 0 ? ws - 1 : 0;
            float v11 = B[i1 * SROW + j1];
            float v01 = B[i0 * SROW + j1];
            float v10 = B[i1 * SROW + j0];
            float v00 = B[i0 * SROW + j0];
            float t11 = (he > 0 && we > 0) ? v11 : 0.0f;
            float t01 = (hs > 0 && we > 0) ? v01 : 0.0f;
            float t10 = (he > 0 && ws > 0) ? v10 : 0.0f;
            float t00 = (hs > 0 && ws > 0) ? v00 : 0.0f;
            float bin_sum = ((t11 - t01) - t10) + t00;   // ref op order

            int area = (he - hs) * (we - ws);
            out[(size_t)r * C_ + c] = (area > 0) ? bin_sum / (float)area : 0.0f;
        }
        __syncthreads();                   // pool done before next do_write
    }
}

// ---- fallback: R11 direct-sum kernel (ws too small) ----
__global__ __launch_bounds__(256) void psroi_direct_kernel(
    const float* __restrict__ fsam,
    const float* __restrict__ box,
    float* __restrict__ out)
{
    int id = blockIdx.x;
    int j  = id & 7;
    int m  = id >> 3;
    int g  = (m < 512) ? j : j + 8;
    int l  = (m < 512) ? m : m - 512;
    int c    = g * 16 + (l >> 5);
    int rblk = l & 31;
    if (c >= C_) return;

    int r = rblk * 256 + (int)threadIdx.x;
    int pw = c % P_;
    int ph = (c / P_) % P_;

    const float* bx = box + (size_t)r * 5;
    int   b  = (int)bx[0];
    float x1 = rintf(bx[1]);
    float y1 = rintf(bx[2]);
    float x2 = rintf(bx[3] + 1.0f);
    float y2 = rintf(bx[4] + 1.0f);

    float roi_w = fmaxf(x2 - x1, 0.1f);
    float roi_h = fmaxf(y2 - y1, 0.1f);

    const float RCP7 = __uint_as_float(0x3E124925u);
    float bin_w = roi_w * RCP7;
    float bin_h = roi_h * RCP7;
    asm volatile("" : "+v"(bin_w), "+v"(bin_h));

    float hs_f = floorf(sep_ma((float)ph,       bin_h, y1));
    float he_f = ceilf (sep_ma((float)(ph + 1), bin_h, y1));
    float ws_f = floorf(sep_ma((float)pw,       bin_w, x1));
    float we_f = ceilf (sep_ma((float)(pw + 1), bin_w, x1));

    int hs = (int)fminf(fmaxf(hs_f, 0.0f), 80.0f);
    int he = (int)fminf(fmaxf(he_f, 0.0f), 80.0f);
    int ws = (int)fminf(fmaxf(ws_f, 0.0f), 80.0f);
    int we = (int)fminf(fmaxf(we_f, 0.0f), 80.0f);

    const float* plane = fsam + ((size_t)b * C_ + c) * (H_ * W_);
    float s = 0.0f;
    for (int y = hs; y < he; ++y) {
        const float* row = plane + y * W_;
        for (int x = ws; x < we; ++x) s += row[x];
    }
    int area = (he - hs) * (we - ws);
    out[(size_t)r * C_ + c] = (area > 0) ? s / (float)area : 0.0f;
}

extern "C" void kernel_launch(void* const* d_in, const int* in_sizes, int n_in,
                              void* d_out, int out_size, void* d_ws, size_t ws_size,
                              hipStream_t stream) {
    const float* fsam = (const float*)d_in[0];
    const float* box  = (const float*)d_in[1];
    float* out = (float*)d_out;

    // ws layout: [0,32) counts (8 ints), [32, 32+8*8192*4) buckets
    size_t need = 32 + (size_t)N_ * R_ * sizeof(int);   // 262176 B
    if (ws_size >= need) {
        int* cnt     = (int*)d_ws;
        int* buckets = (int*)((char*)d_ws + 32);
        bucket_kernel<<<N_, 256, 0, stream>>>(box, cnt, buckets);
        fused_kernel<<<8 * 123, 512, 0, stream>>>(fsam, box, cnt, buckets, out);
    } else {
        psroi_direct_kernel<<<8192, 256, 0, stream>>>(fsam, box, out);
    }
}

// Round 23
// 35.257 us; speedup vs baseline: 1.1053x; 1.1053x over previous
//
#include <hip/hip_runtime.h>

// PSROI pooling: fsam (N=8, C=245, H=80, W=80) f32, box (R=8192, 5) f32
// out (R, 245) f32. out[r, c] = mean over fsam[b, c, hs:he, ws:we].
//
// ARITHMETIC (frozen since R10, DO NOT TOUCH): bin = roi * fl32(1/7)
// (reciprocal multiply, 0x3E124925) and edges = SEPARATELY-rounded
// g*bin + off (asm barriers). Matches ref (absmax <= 0.016 << 0.0725).
//
// R22: R20 base (double-buffer pipeline, 3 barriers/plane — R21's
// single-buffer+extra-barrier regressed) with two scheduling fixes:
//  - grid 512 = 8 images x 64 blocks, np=3-4 planes (c = s+64k): exactly
//    2 resident blocks/CU (53.8KB LDS) from t=0, no ragged 1.44-wave
//    carpet, no dispatch tail; prologue amortized over ~3.8 planes.
//  - bucket kernel: 512 thr x 16 ROIs, 64-lane shfl_up scan + single
//    cross-wave LDS fixup (1 barrier, was 32).
// Fused scan/pool body + edge math verbatim -> bit-identical output.

#define N_ 8
#define C_ 245
#define H_ 80
#define W_ 80
#define R_ 8192
#define P_ 7
#define SROW 84                    // row stride in floats (21 float4)

// XLA-style separately-rounded a*b + c in f32; barriers forbid contraction.
__device__ __forceinline__ float sep_ma(float a, float b, float c) {
    float p = a * b;                 // v_mul_f32, IEEE RN
    asm volatile("" : "+v"(p));      // contraction barrier
    float s = p + c;                 // v_add_f32, IEEE RN
    asm volatile("" : "+v"(s));
    return s;
}

// ---- kernel 1: bucket build, 512 thr, wave-scan (1 barrier) ----
__global__ __launch_bounds__(512) void bucket_kernel(
    const float* __restrict__ box, int* __restrict__ cnt,
    int* __restrict__ buckets)
{
    __shared__ int wtot[8];
    int b = blockIdx.x;                    // image
    int t = threadIdx.x;
    int r0 = t * 16;                       // contiguous range per thread

    unsigned match = 0u;
    int m = 0;
    #pragma unroll
    for (int k = 0; k < 16; ++k) {
        int bb = (int)box[(size_t)(r0 + k) * 5];
        if (bb == b) { match |= 1u << k; ++m; }
    }

    int lane = t & 63, wid = t >> 6;
    int incl = m;
    #pragma unroll
    for (int d = 1; d < 64; d <<= 1) {
        int v = __shfl_up(incl, d);
        if (lane >= d) incl += v;
    }
    if (lane == 63) wtot[wid] = incl;
    __syncthreads();
    int wpref = 0;
    #pragma unroll
    for (int w = 0; w < 8; ++w) wpref += (w < wid) ? wtot[w] : 0;
    int pos = wpref + incl - m;            // exclusive prefix

    #pragma unroll
    for (int k = 0; k < 16; ++k)
        if (match & (1u << k)) buckets[b * R_ + pos++] = r0 + k;
    if (t == 511) cnt[b] = wpref + incl;
}

__device__ __forceinline__ float4 f4_add(float4 a, float4 b) {
    return make_float4(a.x + b.x, a.y + b.y, a.z + b.z, a.w + b.w);
}

// ---- kernel 2: persistent 3-4-plane blocks, double-buffered LDS ----
__global__ __launch_bounds__(512) void fused_kernel(
    const float* __restrict__ fsam,
    const float* __restrict__ box,
    const int* __restrict__ cnt,
    const int* __restrict__ buckets,
    float* __restrict__ out)
{
    __shared__ float S[2][H_ * SROW];      // 2 x 26880 B = 53760 B
    int id  = blockIdx.x;                  // 0..511
    int b   = id & 7;                      // image (XCD swizzle: XCD = b)
    int s   = id >> 3;                     // 0..63
    int np  = (s < 53) ? 4 : 3;            // planes: c = s + 64k
    int tid = threadIdx.x;

    int n  = cnt[b];
    const int* lst = buckets + b * R_;

    // register staging for one plane (1600 float4 / 512 threads)
    float4 ld0, ld1, ld2, ld3;
    auto do_load = [&](int c) {
        const float4* src = (const float4*)(fsam + ((size_t)b * C_ + c) * (H_ * W_));
        ld0 = src[tid];
        ld1 = src[tid + 512];
        ld2 = src[tid + 1024];
        if (tid < 64) ld3 = src[tid + 1536];
    };
    auto wr1 = [&](float* B, int i, float4 v) {
        int row = (int)((unsigned)i / 20u);
        int c4  = i - row * 20;
        ((float4*)B)[row * 21 + c4] = v;
    };
    auto do_write = [&](float* B) {
        wr1(B, tid,        ld0);
        wr1(B, tid +  512, ld1);
        wr1(B, tid + 1024, ld2);
        if (tid < 64) wr1(B, tid + 1536, ld3);
    };

    do_load(s);                            // prologue: plane 0

    for (int k = 0; k < np; ++k) {
        int c = s + 64 * k;
        float* B = S[k & 1];

        do_write(B);
        __syncthreads();                   // raw plane ready in B

        if (k + 1 < np) do_load(s + 64 * (k + 1));   // hides under scans+pool

        // ---- horizontal scan: 80 rows x 4 chunks of 20, in registers ----
        if (tid < 320) {
            int row = tid >> 2, q = tid & 3;
            float4* base = (float4*)B + row * 21 + q * 5;
            float v[20];
            #pragma unroll
            for (int kk = 0; kk < 5; ++kk) {
                float4 t = base[kk];
                v[4*kk+0] = t.x; v[4*kk+1] = t.y; v[4*kk+2] = t.z; v[4*kk+3] = t.w;
            }
            float run = 0.0f;
            #pragma unroll
            for (int j = 0; j < 20; ++j) { run += v[j]; v[j] = run; }
            float incl = run;
            #pragma unroll
            for (int d = 1; d < 4; d <<= 1) {
                float u = __shfl_up(incl, d, 4);
                if (q >= d) incl += u;
            }
            float off = incl - run;
            #pragma unroll
            for (int j = 0; j < 20; ++j) v[j] += off;
            #pragma unroll
            for (int kk = 0; kk < 5; ++kk)
                base[kk] = make_float4(v[4*kk+0], v[4*kk+1], v[4*kk+2], v[4*kk+3]);
        }
        __syncthreads();

        // ---- vertical scan: 20 col-groups x 16 chunks of 5 rows ----
        if (tid < 320) {
            int cg = tid >> 4;             // 0..19
            int ch = tid & 15;             // 0..15
            float4* col = (float4*)B + cg;
            float4 v[5];
            float4 run = make_float4(0.f, 0.f, 0.f, 0.f);
            #pragma unroll
            for (int j = 0; j < 5; ++j) {
                run = f4_add(run, col[(ch * 5 + j) * 21]);
                v[j] = run;
            }
            float4 incl = run;
            #pragma unroll
            for (int d = 1; d < 16; d <<= 1) {
                float4 u;
                u.x = __shfl_up(incl.x, d, 16);
                u.y = __shfl_up(incl.y, d, 16);
                u.z = __shfl_up(incl.z, d, 16);
                u.w = __shfl_up(incl.w, d, 16);
                if (ch >= d) incl = f4_add(incl, u);
            }
            float4 off = make_float4(incl.x - run.x, incl.y - run.y,
                                     incl.z - run.z, incl.w - run.w);
            #pragma unroll
            for (int j = 0; j < 5; ++j)
                col[(ch * 5 + j) * 21] = f4_add(v[j], off);
        }
        __syncthreads();

        // ---- pool this image's ROIs from SAT in B ----
        int ph = (c / P_) % P_;            // block-uniform
        int pw = c % P_;

        for (int i = tid; i < n; i += 512) {
            int r = lst[i];
            const float* bx = box + (size_t)r * 5;

            // ---- R10-frozen edge arithmetic ----
            float x1 = rintf(bx[1]);
            float y1 = rintf(bx[2]);
            float x2 = rintf(bx[3] + 1.0f);
            float y2 = rintf(bx[4] + 1.0f);

            float roi_w = fmaxf(x2 - x1, 0.1f);
            float roi_h = fmaxf(y2 - y1, 0.1f);

            const float RCP7 = __uint_as_float(0x3E124925u); // fl32(1/7)
            float bin_w = roi_w * RCP7;
            float bin_h = roi_h * RCP7;
            asm volatile("" : "+v"(bin_w), "+v"(bin_h));

            float hs_f = floorf(sep_ma((float)ph,       bin_h, y1));
            float he_f = ceilf (sep_ma((float)(ph + 1), bin_h, y1));
            float ws_f = floorf(sep_ma((float)pw,       bin_w, x1));
            float we_f = ceilf (sep_ma((float)(pw + 1), bin_w, x1));

            int hs = (int)fminf(fmaxf(hs_f, 0.0f), 80.0f);
            int he = (int)fminf(fmaxf(he_f, 0.0f), 80.0f);
            int ws = (int)fminf(fmaxf(ws_f, 0.0f), 80.0f);
            int we = (int)fminf(fmaxf(we_f, 0.0f), 80.0f);

            // SAT taps with implicit zero row/col (clamp + select)
            int i1 = he > 0 ? he - 1 : 0, i0 = hs > 0 ? hs - 1 : 0;
            int j1 = we > 0 ? we - 1 : 0, j0 = ws > 0 ? ws - 1 : 0;
            float v11 = B[i1 * SROW + j1];
            float v01 = B[i0 * SROW + j1];
            float v10 = B[i1 * SROW + j0];
            float v00 = B[i0 * SROW + j0];
            float t11 = (he > 0 && we > 0) ? v11 : 0.0f;
            float t01 = (hs > 0 && we > 0) ? v01 : 0.0f;
            float t10 = (he > 0 && ws > 0) ? v10 : 0.0f;
            float t00 = (hs > 0 && ws > 0) ? v00 : 0.0f;
            float bin_sum = ((t11 - t01) - t10) + t00;   // ref op order

            int area = (he - hs) * (we - ws);
            out[(size_t)r * C_ + c] = (area > 0) ? bin_sum / (float)area : 0.0f;
        }
        // no barrier: next iteration writes S[(k+1)&1]; the last reader of
        // that buffer (pool of plane k-1) is 3 barriers upstream.
    }
}

// ---- fallback: R11 direct-sum kernel (ws too small) ----
__global__ __launch_bounds__(256) void psroi_direct_kernel(
    const float* __restrict__ fsam,
    const float* __restrict__ box,
    float* __restrict__ out)
{
    int id = blockIdx.x;
    int j  = id & 7;
    int m  = id >> 3;
    int g  = (m < 512) ? j : j + 8;
    int l  = (m < 512) ? m : m - 512;
    int c    = g * 16 + (l >> 5);
    int rblk = l & 31;
    if (c >= C_) return;

    int r = rblk * 256 + (int)threadIdx.x;
    int pw = c % P_;
    int ph = (c / P_) % P_;

    const float* bx = box + (size_t)r * 5;
    int   b  = (int)bx[0];
    float x1 = rintf(bx[1]);
    float y1 = rintf(bx[2]);
    float x2 = rintf(bx[3] + 1.0f);
    float y2 = rintf(bx[4] + 1.0f);

    float roi_w = fmaxf(x2 - x1, 0.1f);
    float roi_h = fmaxf(y2 - y1, 0.1f);

    const float RCP7 = __uint_as_float(0x3E124925u);
    float bin_w = roi_w * RCP7;
    float bin_h = roi_h * RCP7;
    asm volatile("" : "+v"(bin_w), "+v"(bin_h));

    float hs_f = floorf(sep_ma((float)ph,       bin_h, y1));
    float he_f = ceilf (sep_ma((float)(ph + 1), bin_h, y1));
    float ws_f = floorf(sep_ma((float)pw,       bin_w, x1));
    float we_f = ceilf (sep_ma((float)(pw + 1), bin_w, x1));

    int hs = (int)fminf(fmaxf(hs_f, 0.0f), 80.0f);
    int he = (int)fminf(fmaxf(he_f, 0.0f), 80.0f);
    int ws = (int)fminf(fmaxf(ws_f, 0.0f), 80.0f);
    int we = (int)fminf(fmaxf(we_f, 0.0f), 80.0f);

    const float* plane = fsam + ((size_t)b * C_ + c) * (H_ * W_);
    float s = 0.0f;
    for (int y = hs; y < he; ++y) {
        const float* row = plane + y * W_;
        for (int x = ws; x < we; ++x) s += row[x];
    }
    int area = (he - hs) * (we - ws);
    out[(size_t)r * C_ + c] = (area > 0) ? s / (float)area : 0.0f;
}

extern "C" void kernel_launch(void* const* d_in, const int* in_sizes, int n_in,
                              void* d_out, int out_size, void* d_ws, size_t ws_size,
                              hipStream_t stream) {
    const float* fsam = (const float*)d_in[0];
    const float* box  = (const float*)d_in[1];
    float* out = (float*)d_out;

    // ws layout: [0,32) counts (8 ints), [32, 32+8*8192*4) buckets
    size_t need = 32 + (size_t)N_ * R_ * sizeof(int);   // 262176 B
    if (ws_size >= need) {
        int* cnt     = (int*)d_ws;
        int* buckets = (int*)((char*)d_ws + 32);
        bucket_kernel<<<N_, 512, 0, stream>>>(box, cnt, buckets);
        fused_kernel<<<8 * 64, 512, 0, stream>>>(fsam, box, cnt, buckets, out);
    } else {
        psroi_direct_kernel<<<8192, 256, 0, stream>>>(fsam, box, out);
    }
}